// Round 2
// baseline (726.153 us; speedup 1.0000x reference)
//
#include <hip/hip_runtime.h>

// Problem constants (fixed by reference): B=32, C=256, H=W=128, K=3, reflect pad 1.
constexpr int Bc = 32;
constexpr int Cc = 256;
constexpr int Hc = 128;
constexpr int Wc = 128;
constexpr int HWc = Hc * Wc;
constexpr int CHUNKS = 2;           // channel split (128 ch per block) for occupancy
constexpr int CPC = Cc / CHUNKS;    // 128
constexpr int ROWS = 16;            // output rows per block tile
constexpr int TILES = Hc / ROWS;    // 8

// d_out is poisoned 0xAA before every timed launch; conv kernel atomically
// accumulates per-chunk partials, so zero first (stream-ordered).
__global__ __launch_bounds__(512) void zero_out_kernel(float4* __restrict__ out4) {
    int i = blockIdx.x * 512 + threadIdx.x;   // 512x512 = 262144 float4 = 1,048,576 floats
    out4[i] = make_float4(0.f, 0.f, 0.f, 0.f);
}

// Strategy: each thread owns 4 consecutive output columns of one row and
// accumulates a 6-wide spread (out[p-1..p+4]) so NO per-iteration lane
// shuffles are needed (4 shuffles total at the end). Weights are read with
// wave-uniform addresses -> scalar s_load path, so the DS pipe stays idle.
// Reflect edges (w=0 / w=127) folded in via predicated multipliers eL/eR.
__global__ __launch_bounds__(512, 4) void modbank_kernel(
    const float* __restrict__ x,        // [B,C,H,W]
    const float* __restrict__ ku,       // [9,1,C,3,3]
    const float* __restrict__ kv,       // [9,1,C,3,3]
    const int*   __restrict__ ui,       // [B]
    const int*   __restrict__ vi,       // [B]
    float* __restrict__ out)            // [B,2,H,W]
{
    const int tile  = blockIdx.x;        // 0..7   row tile
    const int b     = blockIdx.y;        // 0..31  batch
    const int chunk = blockIdx.z;        // 0..1   channel chunk
    const int c0    = chunk * CPC;
    const int tid   = threadIdx.x;       // 0..511

    const int w4 = tid & 31;             // float4 index along W (32*4 = 128)
    const int r  = tid >> 5;             // 0..15 row within tile
    const int h  = tile * ROWS + r;
    const int hm = (h == 0)      ? 1      : h - 1;   // reflect
    const int hp = (h == Hc - 1) ? Hc - 2 : h + 1;   // reflect

    const float* pm = x + ((size_t)(b * Cc + c0) * Hc + hm) * Wc + w4 * 4;
    const float* p0 = x + ((size_t)(b * Cc + c0) * Hc + h ) * Wc + w4 * 4;
    const float* pp = x + ((size_t)(b * Cc + c0) * Hc + hp) * Wc + w4 * 4;

    // Wave-uniform weight bases (scalar loads expected)
    const int uview = ui[b];
    const int vview = vi[b];
    const float* wub = ku + ((size_t)uview * Cc + c0) * 9;
    const float* wvb = kv + ((size_t)vview * Cc + c0) * 9;

    // reflect-edge predication multipliers (1 for boundary lane, else 0)
    const float eL = (w4 == 0)  ? 1.f : 0.f;
    const float eR = (w4 == 31) ? 1.f : 0.f;

    // 6-wide accumulators per output: [p-1], [p..p+3], [p+4]
    float  aum1 = 0.f, au4 = 0.f, avm1 = 0.f, av4 = 0.f;
    float4 au = make_float4(0.f, 0.f, 0.f, 0.f);
    float4 av = make_float4(0.f, 0.f, 0.f, 0.f);

    // One input row's contribution. Conv taps: out[j-1]+=kc*x[j],
    // out[j]+=kb*x[j], out[j+1]+=ka*x[j]. tL/tR carry reflect-edge terms.
    auto rowc = [](const float4& v, float tL, float tR,
                   float ka, float kb, float kc,
                   float& am1, float4& a, float& a4) {
        am1 = fmaf(kc, v.x, am1);
        a.x = fmaf(kb, v.x, fmaf(kc, v.y, fmaf(ka, tL, a.x)));
        a.y = fmaf(ka, v.x, fmaf(kb, v.y, fmaf(kc, v.z, a.y)));
        a.z = fmaf(ka, v.y, fmaf(kb, v.z, fmaf(kc, v.w, a.z)));
        a.w = fmaf(ka, v.z, fmaf(kb, v.w, fmaf(kc, tR, a.w)));
        a4  = fmaf(ka, v.w, a4);
    };

    #pragma unroll 2
    for (int ci = 0; ci < CPC; ++ci) {
        const float4 vm = *(const float4*)pm; pm += HWc;
        const float4 v0 = *(const float4*)p0; p0 += HWc;
        const float4 vp = *(const float4*)pp; pp += HWc;
        const float* wu = wub + ci * 9;   // wave-uniform -> s_load
        const float* wv = wvb + ci * 9;

        const float tLm = eL * vm.y, tRm = eR * vm.z;
        const float tL0 = eL * v0.y, tR0 = eR * v0.z;
        const float tLp = eL * vp.y, tRp = eR * vp.z;

        rowc(vm, tLm, tRm, wu[0], wu[1], wu[2], aum1, au, au4);
        rowc(v0, tL0, tR0, wu[3], wu[4], wu[5], aum1, au, au4);
        rowc(vp, tLp, tRp, wu[6], wu[7], wu[8], aum1, au, au4);
        rowc(vm, tLm, tRm, wv[0], wv[1], wv[2], avm1, av, av4);
        rowc(v0, tL0, tR0, wv[3], wv[4], wv[5], avm1, av, av4);
        rowc(vp, tLp, tRp, wv[6], wv[7], wv[8], avm1, av, av4);
    }

    // Cross-thread edge exchange (once per kernel, 4 shuffles total).
    // Left neighbor's a4 is my out[p]; right neighbor's am1 is my out[p+3].
    float fLu = __shfl_up(au4, 1);    if (w4 == 0)  fLu = 0.f;
    float fLv = __shfl_up(av4, 1);    if (w4 == 0)  fLv = 0.f;
    float fRu = __shfl_down(aum1, 1); if (w4 == 31) fRu = 0.f;
    float fRv = __shfl_down(avm1, 1); if (w4 == 31) fRv = 0.f;
    au.x += fLu; au.w += fRu;
    av.x += fLv; av.w += fRv;

    // Accumulate this chunk's 128-channel partial into output.
    float* ou = out + ((size_t)(b * 2 + 0) * Hc + h) * Wc + w4 * 4;
    float* ov = out + ((size_t)(b * 2 + 1) * Hc + h) * Wc + w4 * 4;
    atomicAdd(ou + 0, au.x); atomicAdd(ou + 1, au.y);
    atomicAdd(ou + 2, au.z); atomicAdd(ou + 3, au.w);
    atomicAdd(ov + 0, av.x); atomicAdd(ov + 1, av.y);
    atomicAdd(ov + 2, av.z); atomicAdd(ov + 3, av.w);
}

extern "C" void kernel_launch(void* const* d_in, const int* in_sizes, int n_in,
                              void* d_out, int out_size, void* d_ws, size_t ws_size,
                              hipStream_t stream) {
    const float* x  = (const float*)d_in[0];
    const float* ku = (const float*)d_in[1];
    const float* kv = (const float*)d_in[2];
    const int*   ui = (const int*)d_in[3];
    const int*   vi = (const int*)d_in[4];
    float* out = (float*)d_out;

    zero_out_kernel<<<512, 512, 0, stream>>>((float4*)out);

    dim3 grid(TILES, Bc, CHUNKS);   // 8 x 32 x 2 = 512 blocks, 512 thr each
    modbank_kernel<<<grid, 512, 0, stream>>>(x, ku, kv, ui, vi, out);
}